// Round 17
// baseline (282.217 us; speedup 1.0000x reference)
//
#include <hip/hip_runtime.h>
#include <hip/hip_bf16.h>

typedef __bf16 bf16x8 __attribute__((ext_vector_type(8)));
typedef __bf16 bf16x4 __attribute__((ext_vector_type(4)));
typedef float  f32x4  __attribute__((ext_vector_type(4)));

#define B_   4
#define N_   4096
#define FIN  300
#define FOUT 300
#define FP   320   // padded feature dim (multiple of 32)
#define MT   64    // adjb tile rows
#define KT   64    // adjb tile cols
#define NMT  (N_/MT)
#define NKT  (N_/KT)
#define TILE_BYTES (MT*KT*2)   // 8192
#define STEP_A 16384           // per-K-step LDS: A only (128 rows x 128 B)

// ws layout (bytes)
#define WT_OFF   0                    // Wt   bf16 [FP][FP]
#define D_OFF    (512*1024)           // d    fp32 [B_*N_]
#define TSC_OFF  (1024*1024)          // Tsc  bf16 [B_*N_][FP]
#define YT_OFF   (16*1024*1024)       // Yt bf16 [B_][FP][N_]  ~10.5 MB
#define ADJB_OFF (32*1024*1024)       // adjb bf16 tiled+swizzled [B_][NMT][NKT][8KB]
#define ADJB_BYTES ((size_t)B_ * N_ * N_ * 2)

#define SB() __builtin_amdgcn_sched_barrier(0)

__device__ __forceinline__ void gload_lds16(const void* g, void* l) {
    __builtin_amdgcn_global_load_lds((const __attribute__((address_space(1))) void*)g,
                                     (__attribute__((address_space(3))) void*)l, 16, 0, 0);
}

// ---------------- K0: Wt[f][k] = bf16(W[k][f]), zero-padded ----------------
__global__ void k_wt(const float* __restrict__ W, __bf16* __restrict__ Wt) {
    int t = blockIdx.x * 256 + threadIdx.x;
    if (t >= FP * FP) return;
    int f = t / FP, k = t - f * FP;
    float v = (f < FOUT && k < FIN) ? W[k * FOUT + f] : 0.0f;
    Wt[t] = (__bf16)v;
}

// ---------------- K1a: rowsum only (fallback path) -------------------------
__global__ void k_rowsum(const float* __restrict__ adj, float* __restrict__ d) {
    int row  = blockIdx.x * 4 + (threadIdx.x >> 6);
    int lane = threadIdx.x & 63;
    const float4* p = (const float4*)(adj + (size_t)row * N_);
    float s = 0.0f;
#pragma unroll
    for (int it = 0; it < 16; ++it) {
        float4 v = p[it * 64 + lane];
        s += v.x + v.y + v.z + v.w;
    }
#pragma unroll
    for (int off = 32; off; off >>= 1) s += __shfl_xor(s, off);
    if (lane == 0) d[row] = rsqrtf(s + 1.0f);
}

// ---------------- K1b v2 (R10-verified): rowsum + tiled bf16 copy ----------
// Global tile layout: adjb[(b*NMT+mt)*NKT + kt] is 8 KB = rows [mloc][64
// bf16]; 16-B chunk c of a row at byte mloc*128 + (c*16 ^ ((mloc&7)<<4)).
__global__ __launch_bounds__(512) void k_rowsum_cvt(const float* __restrict__ adj,
                                                    float* __restrict__ d,
                                                    char* __restrict__ adjb) {
    __shared__ __align__(16) char lds[4 * TILE_BYTES];   // 32 KB
    const int mt = blockIdx.x, b = blockIdx.y;
    const int t = threadIdx.x, w = t >> 6, lane = t & 63;
    const int tloc = lane >> 4;                 // which of the 4 tiles in group
    const int chunk = (lane & 15) >> 1;         // 16-B chunk within row
    const int sub8  = (lane & 1) * 8;           // byte offset within chunk
    const size_t rowbase = (size_t)b * N_ + mt * 64;
    char* gbase = adjb + (size_t)((b * NMT + mt) * NKT) * TILE_BYTES;

    float psum[8] = {};
    for (int g = 0; g < 16; ++g) {
#pragma unroll
        for (int rr = 0; rr < 8; ++rr) {
            int r = w * 8 + rr;
            float4 v = *(const float4*)(adj + (rowbase + r) * N_ + g * 256 + lane * 4);
            psum[rr] += v.x + v.y + v.z + v.w;
            bf16x4 o;
            o[0] = (__bf16)v.x; o[1] = (__bf16)v.y; o[2] = (__bf16)v.z; o[3] = (__bf16)v.w;
            int byte = tloc * TILE_BYTES + r * 128 + ((chunk * 16) ^ ((r & 7) << 4)) + sub8;
            *(bf16x4*)(lds + byte) = o;
        }
        __syncthreads();
#pragma unroll
        for (int i = 0; i < 4; ++i) {
            int idx = i * 512 + t;              // 16-B unit 0..2047
            int tl = idx >> 9, off = (idx & 511) * 16;
            *(f32x4*)(gbase + (size_t)(g * 4 + tl) * TILE_BYTES + off) =
                *(const f32x4*)(lds + tl * TILE_BYTES + off);
        }
        __syncthreads();
    }
#pragma unroll
    for (int rr = 0; rr < 8; ++rr) {
        float s = psum[rr];
#pragma unroll
        for (int off = 32; off; off >>= 1) s += __shfl_xor(s, off);
        if (lane == 0) d[rowbase + w * 8 + rr] = rsqrtf(s + 1.0f);
    }
}

// ---------------- K2: Tsc[j][k] = bf16(d[j]*text[j][k]), K zero-padded -----
__global__ void k_tsc(const float* __restrict__ text, const float* __restrict__ d,
                      __bf16* __restrict__ Tsc) {
    int t = blockIdx.x * 256 + threadIdx.x;
    int j = t / FP;
    int k = t - j * FP;
    float v = 0.0f;
    if (k < FIN) v = d[j] * text[(size_t)j * FIN + k];
    Tsc[t] = (__bf16)v;
}

// ---------------- K3: Yt[b][f][j] = sum_k Wt[f][k]*Tsc[b,j][k] -------------
// Plain f-major layout; GEMM B-loads read 64-k slices (2 full 64-B lines per
// f-row, no fetch amplification).
__global__ __launch_bounds__(256) void k_y(const __bf16* __restrict__ Wt,
                                           const __bf16* __restrict__ Tsc,
                                           __bf16* __restrict__ Yt) {
    int b    = blockIdx.y;
    int j0   = blockIdx.x * 64;
    int wave = threadIdx.x >> 6, lane = threadIdx.x & 63;
    int lr = lane & 15, lg = lane >> 4;
    f32x4 acc[5][4] = {};
    for (int k0 = 0; k0 < FP; k0 += 32) {
        bf16x8 a[5], bb[4];
#pragma unroll
        for (int fi = 0; fi < 5; ++fi) {
            int f = (wave * 5 + fi) * 16 + lr;
            a[fi] = *(const bf16x8*)(Wt + (size_t)f * FP + k0 + lg * 8);
        }
#pragma unroll
        for (int ji = 0; ji < 4; ++ji) {
            int j = j0 + ji * 16 + lr;
            bb[ji] = *(const bf16x8*)(Tsc + ((size_t)(b * N_ + j)) * FP + k0 + lg * 8);
        }
#pragma unroll
        for (int fi = 0; fi < 5; ++fi)
#pragma unroll
            for (int ji = 0; ji < 4; ++ji)
                acc[fi][ji] = __builtin_amdgcn_mfma_f32_16x16x32_bf16(a[fi], bb[ji], acc[fi][ji], 0, 0, 0);
    }
#pragma unroll
    for (int fi = 0; fi < 5; ++fi)
#pragma unroll
        for (int ji = 0; ji < 4; ++ji)
#pragma unroll
            for (int r = 0; r < 4; ++r) {
                int f = (wave * 5 + fi) * 16 + lg * 4 + r;
                int j = j0 + ji * 16 + lr;
                Yt[((size_t)b * FP + f) * N_ + j] = (__bf16)acc[fi][ji][r];
            }
}

// ---------------- K4 v8c: out = d_i * (adj @ Yt) + bias --------------------
// R16 + the missing VGPR budget. R16 counter evidence: VGPR_Count=84 while
// B0/B1 alone need 80 -> allocator spilled the pinned-load outputs to
// scratch (R13-equivalent perf, 174 us). Fix: __launch_bounds__(256, 2)
// declares the occupancy this design actually uses (2 blocks/CU x 4 waves
// = 2 waves/SIMD), raising the VGPR cap to ~256. Need ~176: acc 40 +
// B-sets 80 + af 16 + addresses ~40. VGPR_Count must now read ~180-220.
// All pipeline mechanics identical to R16 (counted vmcnt(14), ring-3 A via
// gload_lds, asm-pinned B, tail drain vmcnt(0) before epilogue).
__global__ __launch_bounds__(256, 2) void k_gemm_pipe(const char* __restrict__ adjb,
                                                      const __bf16* __restrict__ yt,
                                                      const float* __restrict__ d,
                                                      const float* __restrict__ bias,
                                                      float* __restrict__ out) {
    __shared__ __align__(16) char smem[3 * STEP_A];   // 48 KB
    const int bid = blockIdx.x;               // 0..511
    const int bx  = bid & 31;                 // 32 m-blocks of 128 rows
    const int b   = (bid >> 5) & 3;           // batch
    const int by  = bid >> 7;                 // 0..3 (80-f panel)
    const int w = threadIdx.x >> 6, lane = threadIdx.x & 63;
    const int lr = lane & 15, lg = lane >> 4;

    // --- A staging plan: 16 chunks; wave w issues cids w*4 .. w*4+3 ---------
    const char* gpA[4];
    int loA[4];
#pragma unroll
    for (int g = 0; g < 4; ++g) {
        int cid = w * 4 + g;                  // 0..15
        gpA[g] = adjb + (size_t)((b * NMT + bx * 2 + (cid >> 3)) * NKT) * TILE_BYTES
                 + (cid & 7) * 1024 + lane * 16;
        loA[g] = cid * 1024;
    }

    // --- B row pointers (identical across the 4 waves -> L1 dedup) ----------
    const char* bp[5];
#pragma unroll
    for (int nt = 0; nt < 5; ++nt)
        bp[nt] = (const char*)(yt + ((size_t)b * FP + by * 80 + nt * 16 + lr) * N_ + lg * 8);

    // --- swizzled A LDS read addresses --------------------------------------
    uint32_t sb = (uint32_t)(uintptr_t)(__attribute__((address_space(3))) char*)smem;
    const int sw = (lr & 7) << 4;
    const uint32_t col0 = (uint32_t)((lg * 16) ^ sw);          // kh=0
    const uint32_t col1 = (uint32_t)(((4 + lg) * 16) ^ sw);    // kh=1
    uint32_t rowA[2];
#pragma unroll
    for (int mi = 0; mi < 2; ++mi)
        rowA[mi] = sb + (w * 32 + mi * 16 + lr) * 128;

    f32x4 acc[2][5] = {};
    bf16x8 B0[5][2], B1[5][2];
    uint32_t oc = 0, on = STEP_A, ot = 2 * STEP_A;

#define STAGEA(OFF, KT_) { _Pragma("unroll") \
    for (int g = 0; g < 4; ++g) \
        gload_lds16(gpA[g] + (size_t)(KT_) * TILE_BYTES, smem + (OFF) + loA[g]); }

// Pinned B loads: asm volatile cannot be sunk or dematerialized (R13 fix).
// k-slice kt -> byte offset kt*128; +64 B = kh=1 half (k = kt*64+32+lg*8).
#define LOADB(BS, kt) { _Pragma("unroll") \
    for (int nt = 0; nt < 5; ++nt) { \
        asm volatile("global_load_dwordx4 %0, %1, off" \
            : "=&v"(BS[nt][0]) : "v"(bp[nt] + (size_t)(kt) * 128) : "memory"); \
        asm volatile("global_load_dwordx4 %0, %1, off" \
            : "=&v"(BS[nt][1]) : "v"(bp[nt] + (size_t)(kt) * 128 + 64) : "memory"); } }

// phase t: consume A slot oc (LDS) + B set BSc (regs, loaded at t-1);
// stage A(t+2) into ot; asm-load B(t+1) into BSn. 14 VMEM/wave -> vmcnt(14).
#define PHASE(BSc, BSn, T)                                                              \
    {                                                                                   \
        int ks = (T) + 2 > NKT - 1 ? NKT - 1 : (T) + 2;                                 \
        int kb = (T) + 1 > NKT - 1 ? NKT - 1 : (T) + 1;                                 \
        SB();                                                                           \
        STAGEA(ot, ks)                                                                  \
        LOADB(BSn, kb)                                                                  \
        SB();                                                                           \
        asm volatile("s_waitcnt vmcnt(14)");   /* A(t) in LDS, B(t) in regs */          \
        SB();                                                                           \
        __builtin_amdgcn_s_barrier();          /* all waves' A(t) chunks visible */     \
        bf16x8 af[2][2];                                                                \
        asm volatile("ds_read_b128 %0, %1" : "=v"(af[0][0]) : "v"(oc + rowA[0] + col0));\
        asm volatile("ds_read_b128 %0, %1" : "=v"(af[0][1]) : "v"(oc + rowA[0] + col1));\
        asm volatile("ds_read_b128 %0, %1" : "=v"(af[1][0]) : "v"(oc + rowA[1] + col0));\
        asm volatile("ds_read_b128 %0, %1" : "=v"(af[1][1]) : "v"(oc + rowA[1] + col1));\
        asm volatile("s_waitcnt lgkmcnt(0)");                                           \
        SB();                                  /* rule 18: fence MFMA below the wait */ \
        __builtin_amdgcn_s_barrier();          /* reads done -> slot reusable */        \
        __builtin_amdgcn_s_setprio(1);                                                  \
        _Pragma("unroll")                                                               \
        for (int kh = 0; kh < 2; ++kh)                                                  \
            _Pragma("unroll")                                                           \
            for (int mi = 0; mi < 2; ++mi)                                              \
                _Pragma("unroll")                                                       \
                for (int nt = 0; nt < 5; ++nt)                                          \
                    acc[mi][nt] = __builtin_amdgcn_mfma_f32_16x16x32_bf16(af[mi][kh], BSc[nt][kh], acc[mi][nt], 0, 0, 0); \
        __builtin_amdgcn_s_setprio(0);                                                  \
        SB();                                                                           \
        uint32_t tmp_ = oc; oc = on; on = ot; ot = tmp_;                                \
    }

    // prologue: A(0), A(1) staged; B(0) in regs -> 18 outstanding/wave.
    STAGEA(0, 0)
    STAGEA(STEP_A, 1)
    LOADB(B0, 0)
    for (int t = 0; t < NKT; t += 2) {
        PHASE(B0, B1, t)
        PHASE(B1, B0, t + 1)
    }
    // Tail drain: retire in-flight asm loads before their dest VGPRs can be
    // reused by epilogue code (compiler can't see the hazard).
    asm volatile("s_waitcnt vmcnt(0)" ::: "memory");
    SB();

    // epilogue: scale by d_i, add bias, store (f < 300 only)
    const int rowb = bx * 128 + w * 32;
#pragma unroll
    for (int mi = 0; mi < 2; ++mi) {
        float di[4];
#pragma unroll
        for (int r = 0; r < 4; ++r)
            di[r] = d[b * N_ + rowb + mi * 16 + lg * 4 + r];
#pragma unroll
        for (int nt = 0; nt < 5; ++nt) {
            int f = by * 80 + nt * 16 + lr;
            if (f < FOUT) {
                float bv = bias[f];
#pragma unroll
                for (int r = 0; r < 4; ++r) {
                    int i = rowb + mi * 16 + lg * 4 + r;
                    out[((size_t)b * N_ + i) * FOUT + f] = di[r] * acc[mi][nt][r] + bv;
                }
            }
        }
    }
#undef STAGEA
#undef LOADB
#undef PHASE
}

// ---------------- Fallback GEMM (fp32 adj direct; only if ws too small) ----
#define FB_LOAD(AV, BV, K0)                                                           \
    {                                                                                 \
        _Pragma("unroll")                                                             \
        for (int mi = 0; mi < 2; ++mi) {                                              \
            const float4* p = (const float4*)(adjf + (size_t)(rowbase + mi * 16 + lr) * N_ + (K0) + lg * 8); \
            float4 v0 = p[0], v1 = p[1];                                              \
            AV[mi][0] = (__bf16)v0.x; AV[mi][1] = (__bf16)v0.y;                       \
            AV[mi][2] = (__bf16)v0.z; AV[mi][3] = (__bf16)v0.w;                       \
            AV[mi][4] = (__bf16)v1.x; AV[mi][5] = (__bf16)v1.y;                       \
            AV[mi][6] = (__bf16)v1.z; AV[mi][7] = (__bf16)v1.w;                       \
        }                                                                             \
        _Pragma("unroll")                                                             \
        for (int nt = 0; nt < 10; ++nt) {                                             \
            int f = wn * 160 + nt * 16 + lr;                                          \
            BV[nt] = *(const bf16x8*)(Yb + (size_t)f * N_ + (K0) + lg * 8);           \
        }                                                                             \
    }
#define FB_MFMA(AV, BV)                                                               \
    {                                                                                 \
        _Pragma("unroll")                                                             \
        for (int mi = 0; mi < 2; ++mi)                                                \
            _Pragma("unroll")                                                         \
            for (int nt = 0; nt < 10; ++nt)                                           \
                acc[mi][nt] = __builtin_amdgcn_mfma_f32_16x16x32_bf16(AV[mi], BV[nt], acc[mi][nt], 0, 0, 0); \
    }

__global__ __launch_bounds__(256) void k_gemm_fb(const float* __restrict__ adj,
                                                 const __bf16* __restrict__ Yt,
                                                 const float* __restrict__ d,
                                                 const float* __restrict__ bias,
                                                 float* __restrict__ out) {
    int b    = blockIdx.y;
    int wave = threadIdx.x >> 6, lane = threadIdx.x & 63;
    int wm = wave & 1, wn = wave >> 1;
    int lr = lane & 15, lg = lane >> 4;
    int rowbase = blockIdx.x * 64 + wm * 32;
    const float*  adjf = adj + (size_t)b * N_ * N_;
    const __bf16* Yb   = Yt + (size_t)b * FP * N_;

    f32x4 acc[2][10] = {};
    bf16x8 aA[2], bA[10], aB[2], bB[10];

    FB_LOAD(aA, bA, 0)
    for (int k0 = 0; k0 < N_ - 64; k0 += 64) {
        FB_LOAD(aB, bB, k0 + 32)
        FB_MFMA(aA, bA)
        FB_LOAD(aA, bA, k0 + 64)
        FB_MFMA(aB, bB)
    }
    FB_LOAD(aB, bB, N_ - 32)
    FB_MFMA(aA, bA)
    FB_MFMA(aB, bB)

#pragma unroll
    for (int mi = 0; mi < 2; ++mi) {
        float di[4];
#pragma unroll
        for (int r = 0; r < 4; ++r)
            di[r] = d[b * N_ + rowbase + mi * 16 + lg * 4 + r];
#pragma unroll
        for (int nt = 0; nt < 10; ++nt) {
            int f = wn * 160 + nt * 16 + lr;
            if (f < FOUT) {
                float bv = bias[f];
#pragma unroll
                for (int r = 0; r < 4; ++r) {
                    int i = rowbase + mi * 16 + lg * 4 + r;
                    out[((size_t)b * N_ + i) * FOUT + f] = di[r] * acc[mi][nt][r] + bv;
                }
            }
        }
    }
}

extern "C" void kernel_launch(void* const* d_in, const int* in_sizes, int n_in,
                              void* d_out, int out_size, void* d_ws, size_t ws_size,
                              hipStream_t stream) {
    const float* text = (const float*)d_in[0];
    const float* adj  = (const float*)d_in[1];
    const float* W    = (const float*)d_in[2];
    const float* bias = (const float*)d_in[3];
    float* out = (float*)d_out;

    char* ws = (char*)d_ws;
    __bf16* Wt   = (__bf16*)(ws + WT_OFF);
    float*  dv   = (float*)(ws + D_OFF);
    __bf16* Tsc  = (__bf16*)(ws + TSC_OFF);
    __bf16* Yt   = (__bf16*)(ws + YT_OFF);
    char*   adjb = ws + ADJB_OFF;

    bool big = ws_size >= (size_t)ADJB_OFF + ADJB_BYTES;

    k_wt<<<dim3((FP * FP + 255) / 256), dim3(256), 0, stream>>>(W, Wt);
    if (big)
        k_rowsum_cvt<<<dim3(NMT, B_), dim3(512), 0, stream>>>(adj, dv, adjb);
    else
        k_rowsum<<<dim3(B_ * N_ / 4), dim3(256), 0, stream>>>(adj, dv);
    k_tsc<<<dim3(B_ * N_ * FP / 256), dim3(256), 0, stream>>>(text, dv, Tsc);
    k_y<<<dim3(N_ / 64, B_), dim3(256), 0, stream>>>(Wt, Tsc, Yt);
    if (big)
        k_gemm_pipe<<<dim3(512), dim3(256), 0, stream>>>(adjb, Yt, dv, bias, out);
    else
        k_gemm_fb<<<dim3(N_ / 64, B_), dim3(256), 0, stream>>>(adj, Yt, dv, bias, out);
}

// Round 18
// 186.352 us; speedup vs baseline: 1.5144x; 1.5144x over previous
//
#include <hip/hip_runtime.h>
#include <hip/hip_bf16.h>

typedef __bf16 bf16x8 __attribute__((ext_vector_type(8)));
typedef __bf16 bf16x4 __attribute__((ext_vector_type(4)));
typedef float  f32x4  __attribute__((ext_vector_type(4)));

#define B_   4
#define N_   4096
#define FIN  300
#define FOUT 300
#define FP   320   // padded feature dim (multiple of 32)
#define MT   64    // adjb tile rows
#define KT   64    // adjb tile cols
#define NMT  (N_/MT)
#define NKT  (N_/KT)
#define TILE_BYTES (MT*KT*2)   // 8192
#define YTILE 2048             // Ytt tile: 16 f x 64 k bf16
#define STEP_B2 26624          // per-K-step LDS: A 16 KB + B 10 KB

// ws layout (bytes)
#define WT_OFF   0                    // Wt   bf16 [FP][FP]
#define D_OFF    (512*1024)           // d    fp32 [B_*N_]
#define TSC_OFF  (1024*1024)          // Tsc  bf16 [B_*N_][FP]
#define YT_OFF   (16*1024*1024)       // Ytt (tiled)  ~10.5 MB
#define ADJB_OFF (32*1024*1024)       // adjb bf16 tiled+swizzled [B_][NMT][NKT][8KB]
#define ADJB_BYTES ((size_t)B_ * N_ * N_ * 2)

#define SB() __builtin_amdgcn_sched_barrier(0)

__device__ __forceinline__ void gload_lds16(const void* g, void* l) {
    __builtin_amdgcn_global_load_lds((const __attribute__((address_space(1))) void*)g,
                                     (__attribute__((address_space(3))) void*)l, 16, 0, 0);
}

// ---------------- K0: Wt[f][k] = bf16(W[k][f]), zero-padded ----------------
__global__ void k_wt(const float* __restrict__ W, __bf16* __restrict__ Wt) {
    int t = blockIdx.x * 256 + threadIdx.x;
    if (t >= FP * FP) return;
    int f = t / FP, k = t - f * FP;
    float v = (f < FOUT && k < FIN) ? W[k * FOUT + f] : 0.0f;
    Wt[t] = (__bf16)v;
}

// ---------------- K1a: rowsum only (fallback path) -------------------------
__global__ void k_rowsum(const float* __restrict__ adj, float* __restrict__ d) {
    int row  = blockIdx.x * 4 + (threadIdx.x >> 6);
    int lane = threadIdx.x & 63;
    const float4* p = (const float4*)(adj + (size_t)row * N_);
    float s = 0.0f;
#pragma unroll
    for (int it = 0; it < 16; ++it) {
        float4 v = p[it * 64 + lane];
        s += v.x + v.y + v.z + v.w;
    }
#pragma unroll
    for (int off = 32; off; off >>= 1) s += __shfl_xor(s, off);
    if (lane == 0) d[row] = rsqrtf(s + 1.0f);
}

// ---------------- K1b v2 (R10-verified): rowsum + tiled bf16 copy ----------
// Global tile layout: adjb[(b*NMT+mt)*NKT + kt] is 8 KB = rows [mloc][64
// bf16]; 16-B chunk c of a row at byte mloc*128 + (c*16 ^ ((mloc&7)<<4)).
__global__ __launch_bounds__(512) void k_rowsum_cvt(const float* __restrict__ adj,
                                                    float* __restrict__ d,
                                                    char* __restrict__ adjb) {
    __shared__ __align__(16) char lds[4 * TILE_BYTES];   // 32 KB
    const int mt = blockIdx.x, b = blockIdx.y;
    const int t = threadIdx.x, w = t >> 6, lane = t & 63;
    const int tloc = lane >> 4;                 // which of the 4 tiles in group
    const int chunk = (lane & 15) >> 1;         // 16-B chunk within row
    const int sub8  = (lane & 1) * 8;           // byte offset within chunk
    const size_t rowbase = (size_t)b * N_ + mt * 64;
    char* gbase = adjb + (size_t)((b * NMT + mt) * NKT) * TILE_BYTES;

    float psum[8] = {};
    for (int g = 0; g < 16; ++g) {
#pragma unroll
        for (int rr = 0; rr < 8; ++rr) {
            int r = w * 8 + rr;
            float4 v = *(const float4*)(adj + (rowbase + r) * N_ + g * 256 + lane * 4);
            psum[rr] += v.x + v.y + v.z + v.w;
            bf16x4 o;
            o[0] = (__bf16)v.x; o[1] = (__bf16)v.y; o[2] = (__bf16)v.z; o[3] = (__bf16)v.w;
            int byte = tloc * TILE_BYTES + r * 128 + ((chunk * 16) ^ ((r & 7) << 4)) + sub8;
            *(bf16x4*)(lds + byte) = o;
        }
        __syncthreads();
#pragma unroll
        for (int i = 0; i < 4; ++i) {
            int idx = i * 512 + t;              // 16-B unit 0..2047
            int tl = idx >> 9, off = (idx & 511) * 16;
            *(f32x4*)(gbase + (size_t)(g * 4 + tl) * TILE_BYTES + off) =
                *(const f32x4*)(lds + tl * TILE_BYTES + off);
        }
        __syncthreads();
    }
#pragma unroll
    for (int rr = 0; rr < 8; ++rr) {
        float s = psum[rr];
#pragma unroll
        for (int off = 32; off; off >>= 1) s += __shfl_xor(s, off);
        if (lane == 0) d[rowbase + w * 8 + rr] = rsqrtf(s + 1.0f);
    }
}

// ---------------- K2: Tsc[j][k] = bf16(d[j]*text[j][k]), K zero-padded -----
__global__ void k_tsc(const float* __restrict__ text, const float* __restrict__ d,
                      __bf16* __restrict__ Tsc) {
    int t = blockIdx.x * 256 + threadIdx.x;
    int j = t / FP;
    int k = t - j * FP;
    float v = 0.0f;
    if (k < FIN) v = d[j] * text[(size_t)j * FIN + k];
    Tsc[t] = (__bf16)v;
}

// ---------------- K3a: plain Yt (fallback): Yt[b][f][j] --------------------
__global__ __launch_bounds__(256) void k_y(const __bf16* __restrict__ Wt,
                                           const __bf16* __restrict__ Tsc,
                                           __bf16* __restrict__ Yt) {
    int b    = blockIdx.y;
    int j0   = blockIdx.x * 64;
    int wave = threadIdx.x >> 6, lane = threadIdx.x & 63;
    int lr = lane & 15, lg = lane >> 4;
    f32x4 acc[5][4] = {};
    for (int k0 = 0; k0 < FP; k0 += 32) {
        bf16x8 a[5], bb[4];
#pragma unroll
        for (int fi = 0; fi < 5; ++fi) {
            int f = (wave * 5 + fi) * 16 + lr;
            a[fi] = *(const bf16x8*)(Wt + (size_t)f * FP + k0 + lg * 8);
        }
#pragma unroll
        for (int ji = 0; ji < 4; ++ji) {
            int j = j0 + ji * 16 + lr;
            bb[ji] = *(const bf16x8*)(Tsc + ((size_t)(b * N_ + j)) * FP + k0 + lg * 8);
        }
#pragma unroll
        for (int fi = 0; fi < 5; ++fi)
#pragma unroll
            for (int ji = 0; ji < 4; ++ji)
                acc[fi][ji] = __builtin_amdgcn_mfma_f32_16x16x32_bf16(a[fi], bb[ji], acc[fi][ji], 0, 0, 0);
    }
#pragma unroll
    for (int fi = 0; fi < 5; ++fi)
#pragma unroll
        for (int ji = 0; ji < 4; ++ji)
#pragma unroll
            for (int r = 0; r < 4; ++r) {
                int f = (wave * 5 + fi) * 16 + lg * 4 + r;
                int j = j0 + ji * 16 + lr;
                Yt[((size_t)b * FP + f) * N_ + j] = (__bf16)acc[fi][ji][r];
            }
}

// ---------------- K3b: tiled+swizzled Ytt for the pipelined GEMM -----------
// Ytt tile (ft, kt): 2 KB = 16 f-rows x 64 k bf16, tile idx (b*20+ft)*64+kt.
__global__ __launch_bounds__(256) void k_y_t(const __bf16* __restrict__ Wt,
                                             const __bf16* __restrict__ Tsc,
                                             char* __restrict__ Ytt) {
    int b    = blockIdx.y;
    int j0   = blockIdx.x * 64;
    int wave = threadIdx.x >> 6, lane = threadIdx.x & 63;
    int lr = lane & 15, lg = lane >> 4;
    f32x4 acc[5][4] = {};
    for (int k0 = 0; k0 < FP; k0 += 32) {
        bf16x8 a[5], bb[4];
#pragma unroll
        for (int fi = 0; fi < 5; ++fi) {
            int f = (wave * 5 + fi) * 16 + lr;
            a[fi] = *(const bf16x8*)(Wt + (size_t)f * FP + k0 + lg * 8);
        }
#pragma unroll
        for (int ji = 0; ji < 4; ++ji) {
            int j = j0 + ji * 16 + lr;
            bb[ji] = *(const bf16x8*)(Tsc + ((size_t)(b * N_ + j)) * FP + k0 + lg * 8);
        }
#pragma unroll
        for (int fi = 0; fi < 5; ++fi)
#pragma unroll
            for (int ji = 0; ji < 4; ++ji)
                acc[fi][ji] = __builtin_amdgcn_mfma_f32_16x16x32_bf16(a[fi], bb[ji], acc[fi][ji], 0, 0, 0);
    }
#pragma unroll
    for (int fi = 0; fi < 5; ++fi)
#pragma unroll
        for (int ji = 0; ji < 4; ++ji)
#pragma unroll
            for (int r = 0; r < 4; ++r) {
                int f = (wave * 5 + fi) * 16 + lg * 4 + r;   // 0..319
                int j = j0 + ji * 16 + lr;                   // 0..4095
                int ft = f >> 4, floc = f & 15;
                int kt = j >> 6, jloc = j & 63;
                size_t base = (size_t)((b * 20 + ft) * 64 + kt) * YTILE;
                int byte = floc * 128 + (((jloc >> 3) * 16) ^ ((floc & 7) << 4)) + (jloc & 7) * 2;
                *(__bf16*)(Ytt + base + byte) = (__bf16)acc[fi][ji][r];
            }
}

// ---------------- K4 v9: R12 structure, ring-2 for 3 blocks/CU -------------
// R17 post-mortem: register-B is dead (allocator splits asm-output live
// ranges through scratch at any VGPR cap; 3 rounds at 174-176 us). Revert to
// R12's LDS-staged-both structure (82 us) and raise TLP instead: ring 3->2
// (52 KB LDS) -> 3 blocks/CU = 3 waves/SIMD (was 2). Stage-distance-1 safety
// by reorder: ENTRY barrier (all waves done reading buf^1, proven by their
// phase t-1 lgkmcnt(0) before MFMA) -> stage(t+1) into buf^1 -> vmcnt(7)
// (tile t's 7 loads, issued at t-1, now oldest) -> barrier (all waves' tile-t
// chunks visible) -> ds_read -> MFMA. Same 2 barriers/step as R12.
// Geometry R12-verbatim: 512 blk x 4 waves (4m x 1n), wave 32m x 80f,
// BM=128 BN=80; 26 real chunks + 2 dups = 7 gloads/wave/step.
__global__ __launch_bounds__(256) void k_gemm_pipe(const char* __restrict__ adjb,
                                                   const char* __restrict__ ytt,
                                                   const float* __restrict__ d,
                                                   const float* __restrict__ bias,
                                                   float* __restrict__ out) {
    __shared__ __align__(16) char smem[2 * STEP_B2];   // 52 KB -> 3 blocks/CU
    const int bid = blockIdx.x;               // 0..511
    const int bx  = bid & 31;                 // 32 m-blocks of 128 rows
    const int b   = (bid >> 5) & 3;           // batch
    const int by  = bid >> 7;                 // 0..3 (80-f panel)
    const int w = threadIdx.x >> 6, lane = threadIdx.x & 63;
    const int lr = lane & 15, lg = lane >> 4;

    // --- staging plan: 26 real chunks (16 A + 10 B); wave w issues cids
    // w*7 .. w*7+6; cid >= 26 wraps to 0,1 (same src+dst as wave 0 -> benign).
    const char* gp[7];
    int st[7], lo[7];
#pragma unroll
    for (int g = 0; g < 7; ++g) {
        int cid = w * 7 + g; if (cid >= 26) cid -= 26;
        if (cid < 16) {  // A: adjb tile (b*NMT + bx*2 + (cid>>3)), chunk cid&7
            gp[g] = adjb + (size_t)((b * NMT + bx * 2 + (cid >> 3)) * NKT) * TILE_BYTES
                    + (cid & 7) * 1024 + lane * 16;
            st[g] = TILE_BYTES;
            lo[g] = cid * 1024;
        } else {         // B: Ytt tile ft = by*5 + (cc>>1), half cc&1
            int cc = cid - 16;                // 0..9
            gp[g] = ytt + (size_t)((b * 20 + by * 5 + (cc >> 1)) * 64) * YTILE
                    + (cc & 1) * 1024 + lane * 16;
            st[g] = YTILE;
            lo[g] = 16384 + cc * 1024;
        }
    }

    // --- swizzled LDS read addresses ---------------------------------------
    uint32_t sb = (uint32_t)(uintptr_t)(__attribute__((address_space(3))) char*)smem;
    const int sw = (lr & 7) << 4;
    const uint32_t col0 = (uint32_t)((lg * 16) ^ sw);          // kh=0
    const uint32_t col1 = (uint32_t)(((4 + lg) * 16) ^ sw);    // kh=1
    uint32_t rowA[2];
#pragma unroll
    for (int mi = 0; mi < 2; ++mi)
        rowA[mi] = sb + (w * 32 + mi * 16 + lr) * 128;
    uint32_t rowB[5];
#pragma unroll
    for (int nt = 0; nt < 5; ++nt) rowB[nt] = sb + 16384 + nt * YTILE + lr * 128;

    f32x4 acc[2][5] = {};
    uint32_t oc = 0, on = STEP_B2;

    // prologue: tile 0 into buf0 -> 7 outstanding per wave
#pragma unroll
    for (int g = 0; g < 7; ++g) gload_lds16(gp[g], smem + lo[g]);

    for (int t = 0; t < NKT; ++t) {
        int ks = t + 1 > NKT - 1 ? NKT - 1 : t + 1;
        SB();
        __builtin_amdgcn_s_barrier();         // entry: all reads of buf^1 done
        SB();
#pragma unroll
        for (int g = 0; g < 7; ++g)           // stage tile t+1 into buf^1
            gload_lds16(gp[g] + (size_t)ks * st[g], smem + on + lo[g]);
        SB();
        asm volatile("s_waitcnt vmcnt(7)");   // tile t (issued at t-1) landed
        SB();
        __builtin_amdgcn_s_barrier();         // all waves' tile-t chunks visible
        bf16x8 af[2][2], bf[5][2];
#pragma unroll
        for (int mi = 0; mi < 2; ++mi) {
            asm volatile("ds_read_b128 %0, %1" : "=v"(af[mi][0]) : "v"(oc + rowA[mi] + col0));
            asm volatile("ds_read_b128 %0, %1" : "=v"(af[mi][1]) : "v"(oc + rowA[mi] + col1));
        }
#pragma unroll
        for (int nt = 0; nt < 5; ++nt) {
            asm volatile("ds_read_b128 %0, %1" : "=v"(bf[nt][0]) : "v"(oc + rowB[nt] + col0));
            asm volatile("ds_read_b128 %0, %1" : "=v"(bf[nt][1]) : "v"(oc + rowB[nt] + col1));
        }
        asm volatile("s_waitcnt lgkmcnt(0)");
        SB();                                  // rule 18: fence MFMA below the wait
        __builtin_amdgcn_s_setprio(1);
#pragma unroll
        for (int kh = 0; kh < 2; ++kh)
#pragma unroll
            for (int mi = 0; mi < 2; ++mi)
#pragma unroll
                for (int nt = 0; nt < 5; ++nt)
                    acc[mi][nt] = __builtin_amdgcn_mfma_f32_16x16x32_bf16(af[mi][kh], bf[nt][kh], acc[mi][nt], 0, 0, 0);
        __builtin_amdgcn_s_setprio(0);
        SB();
        uint32_t tmp = oc; oc = on; on = tmp;  // flip double buffer
    }

    // epilogue: scale by d_i, add bias, store (f < 300 only)
    const int rowb = bx * 128 + w * 32;
#pragma unroll
    for (int mi = 0; mi < 2; ++mi) {
        float di[4];
#pragma unroll
        for (int r = 0; r < 4; ++r)
            di[r] = d[b * N_ + rowb + mi * 16 + lg * 4 + r];
#pragma unroll
        for (int nt = 0; nt < 5; ++nt) {
            int f = by * 80 + nt * 16 + lr;
            if (f < FOUT) {
                float bv = bias[f];
#pragma unroll
                for (int r = 0; r < 4; ++r) {
                    int i = rowb + mi * 16 + lg * 4 + r;
                    out[((size_t)b * N_ + i) * FOUT + f] = di[r] * acc[mi][nt][r] + bv;
                }
            }
        }
    }
}

// ---------------- Fallback GEMM (fp32 adj direct; only if ws too small) ----
#define FB_LOAD(AV, BV, K0)                                                           \
    {                                                                                 \
        _Pragma("unroll")                                                             \
        for (int mi = 0; mi < 2; ++mi) {                                              \
            const float4* p = (const float4*)(adjf + (size_t)(rowbase + mi * 16 + lr) * N_ + (K0) + lg * 8); \
            float4 v0 = p[0], v1 = p[1];                                              \
            AV[mi][0] = (__bf16)v0.x; AV[mi][1] = (__bf16)v0.y;                       \
            AV[mi][2] = (__bf16)v0.z; AV[mi][3] = (__bf16)v0.w;                       \
            AV[mi][4] = (__bf16)v1.x; AV[mi][5] = (__bf16)v1.y;                       \
            AV[mi][6] = (__bf16)v1.z; AV[mi][7] = (__bf16)v1.w;                       \
        }                                                                             \
        _Pragma("unroll")                                                             \
        for (int nt = 0; nt < 10; ++nt) {                                             \
            int f = wn * 160 + nt * 16 + lr;                                          \
            BV[nt] = *(const bf16x8*)(Yb + (size_t)f * N_ + (K0) + lg * 8);           \
        }                                                                             \
    }
#define FB_MFMA(AV, BV)                                                               \
    {                                                                                 \
        _Pragma("unroll")                                                             \
        for (int mi = 0; mi < 2; ++mi)                                                \
            _Pragma("unroll")                                                         \
            for (int nt = 0; nt < 10; ++nt)                                           \
                acc[mi][nt] = __builtin_amdgcn_mfma_f32_16x16x32_bf16(AV[mi], BV[nt], acc[mi][nt], 0, 0, 0); \
    }

__global__ __launch_bounds__(256) void k_gemm_fb(const float* __restrict__ adj,
                                                 const __bf16* __restrict__ Yt,
                                                 const float* __restrict__ d,
                                                 const float* __restrict__ bias,
                                                 float* __restrict__ out) {
    int b    = blockIdx.y;
    int wave = threadIdx.x >> 6, lane = threadIdx.x & 63;
    int wm = wave & 1, wn = wave >> 1;
    int lr = lane & 15, lg = lane >> 4;
    int rowbase = blockIdx.x * 64 + wm * 32;
    const float*  adjf = adj + (size_t)b * N_ * N_;
    const __bf16* Yb   = Yt + (size_t)b * FP * N_;

    f32x4 acc[2][10] = {};
    bf16x8 aA[2], bA[10], aB[2], bB[10];

    FB_LOAD(aA, bA, 0)
    for (int k0 = 0; k0 < N_ - 64; k0 += 64) {
        FB_LOAD(aB, bB, k0 + 32)
        FB_MFMA(aA, bA)
        FB_LOAD(aA, bA, k0 + 64)
        FB_MFMA(aB, bB)
    }
    FB_LOAD(aB, bB, N_ - 32)
    FB_MFMA(aA, bA)
    FB_MFMA(aB, bB)

#pragma unroll
    for (int mi = 0; mi < 2; ++mi) {
        float di[4];
#pragma unroll
        for (int r = 0; r < 4; ++r)
            di[r] = d[b * N_ + rowbase + mi * 16 + lg * 4 + r];
#pragma unroll
        for (int nt = 0; nt < 10; ++nt) {
            int f = wn * 160 + nt * 16 + lr;
            if (f < FOUT) {
                float bv = bias[f];
#pragma unroll
                for (int r = 0; r < 4; ++r) {
                    int i = rowbase + mi * 16 + lg * 4 + r;
                    out[((size_t)b * N_ + i) * FOUT + f] = di[r] * acc[mi][nt][r] + bv;
                }
            }
        }
    }
}

extern "C" void kernel_launch(void* const* d_in, const int* in_sizes, int n_in,
                              void* d_out, int out_size, void* d_ws, size_t ws_size,
                              hipStream_t stream) {
    const float* text = (const float*)d_in[0];
    const float* adj  = (const float*)d_in[1];
    const float* W    = (const float*)d_in[2];
    const float* bias = (const float*)d_in[3];
    float* out = (float*)d_out;

    char* ws = (char*)d_ws;
    __bf16* Wt   = (__bf16*)(ws + WT_OFF);
    float*  dv   = (float*)(ws + D_OFF);
    __bf16* Tsc  = (__bf16*)(ws + TSC_OFF);
    char*   Ybuf = ws + YT_OFF;
    char*   adjb = ws + ADJB_OFF;

    bool big = ws_size >= (size_t)ADJB_OFF + ADJB_BYTES;

    k_wt<<<dim3((FP * FP + 255) / 256), dim3(256), 0, stream>>>(W, Wt);
    if (big)
        k_rowsum_cvt<<<dim3(NMT, B_), dim3(512), 0, stream>>>(adj, dv, adjb);
    else
        k_rowsum<<<dim3(B_ * N_ / 4), dim3(256), 0, stream>>>(adj, dv);
    k_tsc<<<dim3(B_ * N_ * FP / 256), dim3(256), 0, stream>>>(text, dv, Tsc);
    if (big) {
        k_y_t<<<dim3(N_ / 64, B_), dim3(256), 0, stream>>>(Wt, Tsc, Ybuf);
        k_gemm_pipe<<<dim3(512), dim3(256), 0, stream>>>(adjb, Ybuf, dv, bias, out);
    } else {
        k_y<<<dim3(N_ / 64, B_), dim3(256), 0, stream>>>(Wt, Tsc, (__bf16*)Ybuf);
        k_gemm_fb<<<dim3(N_ / 64, B_), dim3(256), 0, stream>>>(adj, (__bf16*)Ybuf, dv, bias, out);
    }
}

// Round 19
// 184.162 us; speedup vs baseline: 1.5324x; 1.0119x over previous
//
#include <hip/hip_runtime.h>
#include <hip/hip_bf16.h>

typedef __bf16 bf16x8 __attribute__((ext_vector_type(8)));
typedef __bf16 bf16x4 __attribute__((ext_vector_type(4)));
typedef float  f32x4  __attribute__((ext_vector_type(4)));

#define B_   4
#define N_   4096
#define FIN  300
#define FOUT 300
#define FP   320   // padded feature dim (multiple of 32)
#define MT   64    // adjb tile rows
#define KT   64    // adjb tile cols
#define NMT  (N_/MT)
#define NKT  (N_/KT)
#define TILE_BYTES (MT*KT*2)   // 8192
#define YTILE 2048             // Ytt tile: 16 f x 64 k bf16
#define STEP_B2 26624          // per-K-step LDS: A 16 KB + B 10 KB

// ws layout (bytes)
#define WT_OFF   0                    // Wt   bf16 [FP][FP]
#define D_OFF    (512*1024)           // d    fp32 [B_*N_]
#define TSC_OFF  (1024*1024)          // Tsc  bf16 [B_*N_][FP]
#define YT_OFF   (16*1024*1024)       // Ytt (tiled)  ~10.5 MB
#define ADJB_OFF (32*1024*1024)       // adjb bf16 tiled+swizzled [B_][NMT][NKT][8KB]
#define ADJB_BYTES ((size_t)B_ * N_ * N_ * 2)

#define SB() __builtin_amdgcn_sched_barrier(0)

__device__ __forceinline__ void gload_lds16(const void* g, void* l) {
    __builtin_amdgcn_global_load_lds((const __attribute__((address_space(1))) void*)g,
                                     (__attribute__((address_space(3))) void*)l, 16, 0, 0);
}

// ---------------- K0: Wt[f][k] = bf16(W[k][f]), zero-padded ----------------
__global__ void k_wt(const float* __restrict__ W, __bf16* __restrict__ Wt) {
    int t = blockIdx.x * 256 + threadIdx.x;
    if (t >= FP * FP) return;
    int f = t / FP, k = t - f * FP;
    float v = (f < FOUT && k < FIN) ? W[k * FOUT + f] : 0.0f;
    Wt[t] = (__bf16)v;
}

// ---------------- K1a: rowsum only (fallback path) -------------------------
__global__ void k_rowsum(const float* __restrict__ adj, float* __restrict__ d) {
    int row  = blockIdx.x * 4 + (threadIdx.x >> 6);
    int lane = threadIdx.x & 63;
    const float4* p = (const float4*)(adj + (size_t)row * N_);
    float s = 0.0f;
#pragma unroll
    for (int it = 0; it < 16; ++it) {
        float4 v = p[it * 64 + lane];
        s += v.x + v.y + v.z + v.w;
    }
#pragma unroll
    for (int off = 32; off; off >>= 1) s += __shfl_xor(s, off);
    if (lane == 0) d[row] = rsqrtf(s + 1.0f);
}

// ---------------- K1b v4: rowsum + tiled/swizzled bf16 copy ----------------
// Same GLOBAL adjb layout as the R10-verified v2 (tile (b,mt,kt) = 8 KB, row
// mloc at byte mloc*128, 16-B chunk c at (c*16)^((mloc&7)<<4)).
// v4 = TLP fix: v2's grid (256 blocks x 8 waves) was 1 block/CU = 8 waves/CU
// (25% of capacity, grid-limited). v4: 16-row quarter-panels -> 1024 blocks
// x 256 thr = 4 blocks/CU = 16 waves/CU. Swizzle algebra unchanged:
// global row = q*16+rl, (q*16+rl)&7 == rl&7.
__global__ __launch_bounds__(256) void k_rowsum_cvt(const float* __restrict__ adj,
                                                    float* __restrict__ d,
                                                    char* __restrict__ adjb) {
    __shared__ __align__(16) char lds[4 * 2048];   // 4 tiles x 16 rows = 8 KB
    const int bx = blockIdx.x, b = blockIdx.y;     // bx: 0..255
    const int mt = bx >> 2, q = bx & 3;            // 64-row tile, 16-row quarter
    const int t = threadIdx.x, w = t >> 6, lane = t & 63;
    const int tloc = lane >> 4;                 // which of the 4 tiles in group
    const int chunk = (lane & 15) >> 1;         // 16-B chunk within row
    const int sub8  = (lane & 1) * 8;           // byte offset within chunk
    const size_t rowbase = (size_t)b * N_ + mt * 64 + q * 16;
    char* gbase = adjb + (size_t)((b * NMT + mt) * NKT) * TILE_BYTES + q * 2048;

    float psum[4] = {};
    for (int g = 0; g < 16; ++g) {
        // phase 1: read 16 rows x 256 cols, convert, ds_write in tile layout
#pragma unroll
        for (int rr = 0; rr < 4; ++rr) {
            int rl = w * 4 + rr;                 // local row 0..15
            float4 v = *(const float4*)(adj + (rowbase + rl) * N_ + g * 256 + lane * 4);
            psum[rr] += v.x + v.y + v.z + v.w;
            bf16x4 o;
            o[0] = (__bf16)v.x; o[1] = (__bf16)v.y; o[2] = (__bf16)v.z; o[3] = (__bf16)v.w;
            int byte = tloc * 2048 + rl * 128 + ((chunk * 16) ^ ((rl & 7) << 4)) + sub8;
            *(bf16x4*)(lds + byte) = o;
        }
        __syncthreads();
        // phase 2: linear copy-out (rows q*16..+16 of tiles kt = 4g..4g+3)
#pragma unroll
        for (int i = 0; i < 2; ++i) {
            int idx = i * 256 + t;              // 16-B unit 0..511
            int tl = idx >> 7, off = (idx & 127) * 16;
            *(f32x4*)(gbase + (size_t)(g * 4 + tl) * TILE_BYTES + off) =
                *(const f32x4*)(lds + tl * 2048 + off);
        }
        __syncthreads();
    }
    // rowsum reduce: lane covered disjoint cols {g*256 + lane*4 ..+3}
#pragma unroll
    for (int rr = 0; rr < 4; ++rr) {
        float s = psum[rr];
#pragma unroll
        for (int off = 32; off; off >>= 1) s += __shfl_xor(s, off);
        if (lane == 0) d[rowbase + w * 4 + rr] = rsqrtf(s + 1.0f);
    }
}

// ---------------- K2: Tsc[j][k] = bf16(d[j]*text[j][k]), K zero-padded -----
__global__ void k_tsc(const float* __restrict__ text, const float* __restrict__ d,
                      __bf16* __restrict__ Tsc) {
    int t = blockIdx.x * 256 + threadIdx.x;
    int j = t / FP;
    int k = t - j * FP;
    float v = 0.0f;
    if (k < FIN) v = d[j] * text[(size_t)j * FIN + k];
    Tsc[t] = (__bf16)v;
}

// ---------------- K3a: plain Yt (fallback): Yt[b][f][j] --------------------
__global__ __launch_bounds__(256) void k_y(const __bf16* __restrict__ Wt,
                                           const __bf16* __restrict__ Tsc,
                                           __bf16* __restrict__ Yt) {
    int b    = blockIdx.y;
    int j0   = blockIdx.x * 64;
    int wave = threadIdx.x >> 6, lane = threadIdx.x & 63;
    int lr = lane & 15, lg = lane >> 4;
    f32x4 acc[5][4] = {};
    for (int k0 = 0; k0 < FP; k0 += 32) {
        bf16x8 a[5], bb[4];
#pragma unroll
        for (int fi = 0; fi < 5; ++fi) {
            int f = (wave * 5 + fi) * 16 + lr;
            a[fi] = *(const bf16x8*)(Wt + (size_t)f * FP + k0 + lg * 8);
        }
#pragma unroll
        for (int ji = 0; ji < 4; ++ji) {
            int j = j0 + ji * 16 + lr;
            bb[ji] = *(const bf16x8*)(Tsc + ((size_t)(b * N_ + j)) * FP + k0 + lg * 8);
        }
#pragma unroll
        for (int fi = 0; fi < 5; ++fi)
#pragma unroll
            for (int ji = 0; ji < 4; ++ji)
                acc[fi][ji] = __builtin_amdgcn_mfma_f32_16x16x32_bf16(a[fi], bb[ji], acc[fi][ji], 0, 0, 0);
    }
#pragma unroll
    for (int fi = 0; fi < 5; ++fi)
#pragma unroll
        for (int ji = 0; ji < 4; ++ji)
#pragma unroll
            for (int r = 0; r < 4; ++r) {
                int f = (wave * 5 + fi) * 16 + lg * 4 + r;
                int j = j0 + ji * 16 + lr;
                Yt[((size_t)b * FP + f) * N_ + j] = (__bf16)acc[fi][ji][r];
            }
}

// ---------------- K3b: tiled+swizzled Ytt for the pipelined GEMM -----------
// Ytt tile (ft, kt): 2 KB = 16 f-rows x 64 k bf16, tile idx (b*20+ft)*64+kt.
__global__ __launch_bounds__(256) void k_y_t(const __bf16* __restrict__ Wt,
                                             const __bf16* __restrict__ Tsc,
                                             char* __restrict__ Ytt) {
    int b    = blockIdx.y;
    int j0   = blockIdx.x * 64;
    int wave = threadIdx.x >> 6, lane = threadIdx.x & 63;
    int lr = lane & 15, lg = lane >> 4;
    f32x4 acc[5][4] = {};
    for (int k0 = 0; k0 < FP; k0 += 32) {
        bf16x8 a[5], bb[4];
#pragma unroll
        for (int fi = 0; fi < 5; ++fi) {
            int f = (wave * 5 + fi) * 16 + lr;
            a[fi] = *(const bf16x8*)(Wt + (size_t)f * FP + k0 + lg * 8);
        }
#pragma unroll
        for (int ji = 0; ji < 4; ++ji) {
            int j = j0 + ji * 16 + lr;
            bb[ji] = *(const bf16x8*)(Tsc + ((size_t)(b * N_ + j)) * FP + k0 + lg * 8);
        }
#pragma unroll
        for (int fi = 0; fi < 5; ++fi)
#pragma unroll
            for (int ji = 0; ji < 4; ++ji)
                acc[fi][ji] = __builtin_amdgcn_mfma_f32_16x16x32_bf16(a[fi], bb[ji], acc[fi][ji], 0, 0, 0);
    }
#pragma unroll
    for (int fi = 0; fi < 5; ++fi)
#pragma unroll
        for (int ji = 0; ji < 4; ++ji)
#pragma unroll
            for (int r = 0; r < 4; ++r) {
                int f = (wave * 5 + fi) * 16 + lg * 4 + r;   // 0..319
                int j = j0 + ji * 16 + lr;                   // 0..4095
                int ft = f >> 4, floc = f & 15;
                int kt = j >> 6, jloc = j & 63;
                size_t base = (size_t)((b * 20 + ft) * 64 + kt) * YTILE;
                int byte = floc * 128 + (((jloc >> 3) * 16) ^ ((floc & 7) << 4)) + (jloc & 7) * 2;
                *(__bf16*)(Ytt + base + byte) = (__bf16)acc[fi][ji][r];
            }
}

// ---------------- K4 v9 (R18-verbatim, best: ~80 us): ----------------------
// Ring-2 (52 KB) -> 3 blocks/CU = 3 waves/SIMD. Stage-distance-1 by reorder:
// entry barrier -> stage(t+1) into buf^1 -> vmcnt(7) -> barrier -> ds_read
// -> MFMA. 512 blk x 4 waves (4m x 1n), wave 32m x 80f, BM=128 BN=80.
__global__ __launch_bounds__(256) void k_gemm_pipe(const char* __restrict__ adjb,
                                                   const char* __restrict__ ytt,
                                                   const float* __restrict__ d,
                                                   const float* __restrict__ bias,
                                                   float* __restrict__ out) {
    __shared__ __align__(16) char smem[2 * STEP_B2];   // 52 KB -> 3 blocks/CU
    const int bid = blockIdx.x;               // 0..511
    const int bx  = bid & 31;                 // 32 m-blocks of 128 rows
    const int b   = (bid >> 5) & 3;           // batch
    const int by  = bid >> 7;                 // 0..3 (80-f panel)
    const int w = threadIdx.x >> 6, lane = threadIdx.x & 63;
    const int lr = lane & 15, lg = lane >> 4;

    const char* gp[7];
    int st[7], lo[7];
#pragma unroll
    for (int g = 0; g < 7; ++g) {
        int cid = w * 7 + g; if (cid >= 26) cid -= 26;
        if (cid < 16) {  // A: adjb tile (b*NMT + bx*2 + (cid>>3)), chunk cid&7
            gp[g] = adjb + (size_t)((b * NMT + bx * 2 + (cid >> 3)) * NKT) * TILE_BYTES
                    + (cid & 7) * 1024 + lane * 16;
            st[g] = TILE_BYTES;
            lo[g] = cid * 1024;
        } else {         // B: Ytt tile ft = by*5 + (cc>>1), half cc&1
            int cc = cid - 16;                // 0..9
            gp[g] = ytt + (size_t)((b * 20 + by * 5 + (cc >> 1)) * 64) * YTILE
                    + (cc & 1) * 1024 + lane * 16;
            st[g] = YTILE;
            lo[g] = 16384 + cc * 1024;
        }
    }

    uint32_t sb = (uint32_t)(uintptr_t)(__attribute__((address_space(3))) char*)smem;
    const int sw = (lr & 7) << 4;
    const uint32_t col0 = (uint32_t)((lg * 16) ^ sw);          // kh=0
    const uint32_t col1 = (uint32_t)(((4 + lg) * 16) ^ sw);    // kh=1
    uint32_t rowA[2];
#pragma unroll
    for (int mi = 0; mi < 2; ++mi)
        rowA[mi] = sb + (w * 32 + mi * 16 + lr) * 128;
    uint32_t rowB[5];
#pragma unroll
    for (int nt = 0; nt < 5; ++nt) rowB[nt] = sb + 16384 + nt * YTILE + lr * 128;

    f32x4 acc[2][5] = {};
    uint32_t oc = 0, on = STEP_B2;

    // prologue: tile 0 into buf0 -> 7 outstanding per wave
#pragma unroll
    for (int g = 0; g < 7; ++g) gload_lds16(gp[g], smem + lo[g]);

    for (int t = 0; t < NKT; ++t) {
        int ks = t + 1 > NKT - 1 ? NKT - 1 : t + 1;
        SB();
        __builtin_amdgcn_s_barrier();         // entry: all reads of buf^1 done
        SB();
#pragma unroll
        for (int g = 0; g < 7; ++g)           // stage tile t+1 into buf^1
            gload_lds16(gp[g] + (size_t)ks * st[g], smem + on + lo[g]);
        SB();
        asm volatile("s_waitcnt vmcnt(7)");   // tile t (issued at t-1) landed
        SB();
        __builtin_amdgcn_s_barrier();         // all waves' tile-t chunks visible
        bf16x8 af[2][2], bf[5][2];
#pragma unroll
        for (int mi = 0; mi < 2; ++mi) {
            asm volatile("ds_read_b128 %0, %1" : "=v"(af[mi][0]) : "v"(oc + rowA[mi] + col0));
            asm volatile("ds_read_b128 %0, %1" : "=v"(af[mi][1]) : "v"(oc + rowA[mi] + col1));
        }
#pragma unroll
        for (int nt = 0; nt < 5; ++nt) {
            asm volatile("ds_read_b128 %0, %1" : "=v"(bf[nt][0]) : "v"(oc + rowB[nt] + col0));
            asm volatile("ds_read_b128 %0, %1" : "=v"(bf[nt][1]) : "v"(oc + rowB[nt] + col1));
        }
        asm volatile("s_waitcnt lgkmcnt(0)");
        SB();                                  // rule 18: fence MFMA below the wait
        __builtin_amdgcn_s_setprio(1);
#pragma unroll
        for (int kh = 0; kh < 2; ++kh)
#pragma unroll
            for (int mi = 0; mi < 2; ++mi)
#pragma unroll
                for (int nt = 0; nt < 5; ++nt)
                    acc[mi][nt] = __builtin_amdgcn_mfma_f32_16x16x32_bf16(af[mi][kh], bf[nt][kh], acc[mi][nt], 0, 0, 0);
        __builtin_amdgcn_s_setprio(0);
        SB();
        uint32_t tmp = oc; oc = on; on = tmp;  // flip double buffer
    }

    // epilogue: scale by d_i, add bias, store (f < 300 only)
    const int rowb = bx * 128 + w * 32;
#pragma unroll
    for (int mi = 0; mi < 2; ++mi) {
        float di[4];
#pragma unroll
        for (int r = 0; r < 4; ++r)
            di[r] = d[b * N_ + rowb + mi * 16 + lg * 4 + r];
#pragma unroll
        for (int nt = 0; nt < 5; ++nt) {
            int f = by * 80 + nt * 16 + lr;
            if (f < FOUT) {
                float bv = bias[f];
#pragma unroll
                for (int r = 0; r < 4; ++r) {
                    int i = rowb + mi * 16 + lg * 4 + r;
                    out[((size_t)b * N_ + i) * FOUT + f] = di[r] * acc[mi][nt][r] + bv;
                }
            }
        }
    }
}

// ---------------- Fallback GEMM (fp32 adj direct; only if ws too small) ----
#define FB_LOAD(AV, BV, K0)                                                           \
    {                                                                                 \
        _Pragma("unroll")                                                             \
        for (int mi = 0; mi < 2; ++mi) {                                              \
            const float4* p = (const float4*)(adjf + (size_t)(rowbase + mi * 16 + lr) * N_ + (K0) + lg * 8); \
            float4 v0 = p[0], v1 = p[1];                                              \
            AV[mi][0] = (__bf16)v0.x; AV[mi][1] = (__bf16)v0.y;                       \
            AV[mi][2] = (__bf16)v0.z; AV[mi][3] = (__bf16)v0.w;                       \
            AV[mi][4] = (__bf16)v1.x; AV[mi][5] = (__bf16)v1.y;                       \
            AV[mi][6] = (__bf16)v1.z; AV[mi][7] = (__bf16)v1.w;                       \
        }                                                                             \
        _Pragma("unroll")                                                             \
        for (int nt = 0; nt < 10; ++nt) {                                             \
            int f = wn * 160 + nt * 16 + lr;                                          \
            BV[nt] = *(const bf16x8*)(Yb + (size_t)f * N_ + (K0) + lg * 8);           \
        }                                                                             \
    }
#define FB_MFMA(AV, BV)                                                               \
    {                                                                                 \
        _Pragma("unroll")                                                             \
        for (int mi = 0; mi < 2; ++mi)                                                \
            _Pragma("unroll")                                                         \
            for (int nt = 0; nt < 10; ++nt)                                           \
                acc[mi][nt] = __builtin_amdgcn_mfma_f32_16x16x32_bf16(AV[mi], BV[nt], acc[mi][nt], 0, 0, 0); \
    }

__global__ __launch_bounds__(256) void k_gemm_fb(const float* __restrict__ adj,
                                                 const __bf16* __restrict__ Yt,
                                                 const float* __restrict__ d,
                                                 const float* __restrict__ bias,
                                                 float* __restrict__ out) {
    int b    = blockIdx.y;
    int wave = threadIdx.x >> 6, lane = threadIdx.x & 63;
    int wm = wave & 1, wn = wave >> 1;
    int lr = lane & 15, lg = lane >> 4;
    int rowbase = blockIdx.x * 64 + wm * 32;
    const float*  adjf = adj + (size_t)b * N_ * N_;
    const __bf16* Yb   = Yt + (size_t)b * FP * N_;

    f32x4 acc[2][10] = {};
    bf16x8 aA[2], bA[10], aB[2], bB[10];

    FB_LOAD(aA, bA, 0)
    for (int k0 = 0; k0 < N_ - 64; k0 += 64) {
        FB_LOAD(aB, bB, k0 + 32)
        FB_MFMA(aA, bA)
        FB_LOAD(aA, bA, k0 + 64)
        FB_MFMA(aB, bB)
    }
    FB_LOAD(aB, bB, N_ - 32)
    FB_MFMA(aA, bA)
    FB_MFMA(aB, bB)

#pragma unroll
    for (int mi = 0; mi < 2; ++mi) {
        float di[4];
#pragma unroll
        for (int r = 0; r < 4; ++r)
            di[r] = d[b * N_ + rowbase + mi * 16 + lg * 4 + r];
#pragma unroll
        for (int nt = 0; nt < 10; ++nt) {
            int f = wn * 160 + nt * 16 + lr;
            if (f < FOUT) {
                float bv = bias[f];
#pragma unroll
                for (int r = 0; r < 4; ++r) {
                    int i = rowbase + mi * 16 + lg * 4 + r;
                    out[((size_t)b * N_ + i) * FOUT + f] = di[r] * acc[mi][nt][r] + bv;
                }
            }
        }
    }
}

extern "C" void kernel_launch(void* const* d_in, const int* in_sizes, int n_in,
                              void* d_out, int out_size, void* d_ws, size_t ws_size,
                              hipStream_t stream) {
    const float* text = (const float*)d_in[0];
    const float* adj  = (const float*)d_in[1];
    const float* W    = (const float*)d_in[2];
    const float* bias = (const float*)d_in[3];
    float* out = (float*)d_out;

    char* ws = (char*)d_ws;
    __bf16* Wt   = (__bf16*)(ws + WT_OFF);
    float*  dv   = (float*)(ws + D_OFF);
    __bf16* Tsc  = (__bf16*)(ws + TSC_OFF);
    char*   Ybuf = ws + YT_OFF;
    char*   adjb = ws + ADJB_OFF;

    bool big = ws_size >= (size_t)ADJB_OFF + ADJB_BYTES;

    k_wt<<<dim3((FP * FP + 255) / 256), dim3(256), 0, stream>>>(W, Wt);
    if (big)
        k_rowsum_cvt<<<dim3(NMT * 4, B_), dim3(256), 0, stream>>>(adj, dv, adjb);
    else
        k_rowsum<<<dim3(B_ * N_ / 4), dim3(256), 0, stream>>>(adj, dv);
    k_tsc<<<dim3(B_ * N_ * FP / 256), dim3(256), 0, stream>>>(text, dv, Tsc);
    if (big) {
        k_y_t<<<dim3(N_ / 64, B_), dim3(256), 0, stream>>>(Wt, Tsc, Ybuf);
        k_gemm_pipe<<<dim3(512), dim3(256), 0, stream>>>(adjb, Ybuf, dv, bias, out);
    } else {
        k_y<<<dim3(N_ / 64, B_), dim3(256), 0, stream>>>(Wt, Tsc, (__bf16*)Ybuf);
        k_gemm_fb<<<dim3(N_ / 64, B_), dim3(256), 0, stream>>>(adj, (__bf16*)Ybuf, dv, bias, out);
    }
}